// Round 10
// baseline (192.380 us; speedup 1.0000x reference)
//
#include <hip/hip_runtime.h>
#include <hip/hip_bf16.h>

#define B_DIM 8192
#define D_DIM 256
#define GRID_GEMM 2048
#define NCT 8    // 32-col tiles per block (256 cols per block)
#define NSUB 16  // staged 8KB sub-tiles per block (2 K-halves per col-tile)

constexpr float INV_T = 14.285714285714286f;   // 1/0.07; also the logsumexp shift M

typedef __bf16 bf16x8 __attribute__((ext_vector_type(8)));
typedef float  f32x16 __attribute__((ext_vector_type(16)));

#define GLOBAL_U32(p) ((const __attribute__((address_space(1))) unsigned int*)(p))
#define LDS_U32(p)    ((__attribute__((address_space(3))) unsigned int*)(p))

// s_waitcnt imm (gfx9): vm[3:0]=bits3:0, exp=bits6:4, lgkm=bits11:8, vm[5:4]=bits15:14
// vmcnt(4), expcnt/lgkmcnt = no-wait:
#define WAITCNT_VM4 0x0F74

__device__ inline unsigned short f2bf(float f) {
    union { float f; unsigned u; } x; x.f = f;
    unsigned r = x.u + 0x7fffu + ((x.u >> 16) & 1u);  // RNE
    return (unsigned short)(r >> 16);
}

// Kernel 1: q = normalize(h+r), t = normalize(t), BOTH stored in MFMA
// FRAGMENT order: 16B-slot ((row>>5)*16 + ks)*64 + hi*32 + (row&31) holds
// row's k = ks*16 + hi*8 + j (verified R5/R7/R8). Makes the GEMM's
// A-prologue and LDS staging/reads fully linear.
// Block 0 additionally zeroes rowsum/diagsum/ticket.
__global__ __launch_bounds__(256) void norm_kernel(
    const float* __restrict__ h, const float* __restrict__ r,
    const float* __restrict__ t,
    unsigned short* __restrict__ qws, unsigned short* __restrict__ tws,
    float* __restrict__ rowsum, float* __restrict__ diagsum, int* __restrict__ ticket)
{
    if (blockIdx.x == 0) {
        float4* rs4 = (float4*)rowsum;
#pragma unroll
        for (int i = 0; i < 8; ++i)
            rs4[threadIdx.x * 8 + i] = make_float4(0.f, 0.f, 0.f, 0.f);
        if (threadIdx.x == 0) { *diagsum = 0.f; *ticket = 0; }
    }

    const int wave = threadIdx.x >> 6;
    const int lane = threadIdx.x & 63;
    const int wg   = blockIdx.x * 4 + wave;      // 0..4095, 2 rows each

    // fragment store coords for this lane (k = 4*lane + j):
    const int ks  = lane >> 2;
    const int hi2 = (lane >> 1) & 1;
    const int sub = lane & 1;

#pragma unroll
    for (int i = 0; i < 2; ++i) {
        const int row = wg * 2 + i;              // 0..8191
        // ---- q = normalize(h+r) ----
        {
            float4 a = ((const float4*)h)[row * 64 + lane];
            float4 b = ((const float4*)r)[row * 64 + lane];
            float4 v = make_float4(a.x + b.x, a.y + b.y, a.z + b.z, a.w + b.w);
            float s = v.x * v.x + v.y * v.y + v.z * v.z + v.w * v.w;
#pragma unroll
            for (int off = 32; off; off >>= 1) s += __shfl_xor(s, off, 64);
            float scale = 1.0f / fmaxf(sqrtf(s), 1e-12f);
            ushort4 o;
            o.x = f2bf(v.x * scale); o.y = f2bf(v.y * scale);
            o.z = f2bf(v.z * scale); o.w = f2bf(v.w * scale);
            size_t slot16 = ((size_t)((row >> 5) * 16 + ks) * 64
                             + (size_t)(hi2 * 32 + (row & 31)));
            *(ushort4*)((unsigned char*)qws + slot16 * 16 + sub * 8) = o;
        }
        // ---- t = normalize(t) ----
        {
            float4 v = ((const float4*)t)[row * 64 + lane];
            float s = v.x * v.x + v.y * v.y + v.z * v.z + v.w * v.w;
#pragma unroll
            for (int off = 32; off; off >>= 1) s += __shfl_xor(s, off, 64);
            float scale = 1.0f / fmaxf(sqrtf(s), 1e-12f);
            ushort4 o;
            o.x = f2bf(v.x * scale); o.y = f2bf(v.y * scale);
            o.z = f2bf(v.z * scale); o.w = f2bf(v.w * scale);
            size_t slot16 = ((size_t)((row >> 5) * 16 + ks) * 64
                             + (size_t)(hi2 * 32 + (row & 31)));
            *(ushort4*)((unsigned char*)tws + slot16 * 16 + sub * 8) = o;
        }
    }
}

// Kernel 2: register-thin variant. R9's decisive fact: occupancy stayed at
// 2 waves/SIMD with 33KB LDS -> the cap is the unified VGPR+AGPR footprint
// (~172/wave: a[2][16]=128 VGPR + 64 acc). This round halves the per-wave
// row count to 32 (a[16]=64 VGPR, acc 16, rowacc 16 -> ~120 unified), so
// registers AND LDS both permit 4 blocks/CU = 16 waves/CU (2x R8).
// Block = 4 waves x 32 rows = 128 rows x 256 cols; grid 2048 = 64 rb x 32 cc.
// Staging is R9's verified skeleton: 8KB fragment-order sub-tiles, ring 4
// (33KB), prefetch distance 2, vmcnt(4), raw barrier, dummy tail. Per-CU
// MFMA/LDS/exp totals are identical to R8 -- only concurrency changes.
// __launch_bounds__ stays (256,2): (256,4) hard-caps unified regs at 128
// and R6 showed the allocator spills catastrophically when over.
__global__ __launch_bounds__(256, 2) void gemm_lse_kernel(
    const unsigned char* __restrict__ qws, const unsigned char* __restrict__ tws,
    float* __restrict__ rowsum, float* __restrict__ diagsum,
    int* __restrict__ ticket, float* __restrict__ out)
{
    __shared__ __align__(16) unsigned char ldsB[4][8192];   // 32 KB ring
    __shared__ float wred[4];
    __shared__ int lastflag;

    const int tid  = threadIdx.x;
    const int lane = tid & 63;
    const int w    = tid >> 6;
    const int l31  = lane & 31;
    const int hi   = lane >> 5;

    const int cc   = blockIdx.x & 31;        // col chunk (fast -> XCD locality)
    const int rb   = blockIdx.x >> 5;        // row block 0..63
    const int row0 = rb * 128 + w * 32;      // this wave's 32 rows
    const int col0 = cc * 256;
    const int subt0 = cc * 16;               // first 8KB sub-tile of this chunk

    // stage 8KB sub-tile s (linear in fragment order) into ring buffer bufi
#define STAGE(s, bufi)                                                       \
    {                                                                        \
        const unsigned char* gs = tws + (size_t)(subt0 + (s)) * 8192;        \
        _Pragma("unroll")                                                    \
        for (int it = 0; it < 2; ++it)                                       \
            __builtin_amdgcn_global_load_lds(                                \
                GLOBAL_U32(gs + (it * 256 + tid) * 16),                      \
                LDS_U32(&ldsB[bufi][(it * 256 + tid) * 16]), 16, 0, 0);      \
    }

    // prologue: sub-tiles 0 and 1 in flight before the A-fragment loads
    STAGE(0, 0);
    STAGE(1, 1);

    // ---- A fragments in registers: rows row0..row0+31, full K=256 ----
    // frag-order qws: byte = row0*512 + ks*1024 + lane*16
    // -> row = row0 + l31, k = ks*16 + hi*8 + j
    bf16x8 a[16];
    {
        const unsigned char* abase = qws + (size_t)row0 * 512 + lane * 16;
#pragma unroll
        for (int ks = 0; ks < 16; ++ks)
            a[ks] = *(const bf16x8*)(abase + ks * 1024);
    }

    f32x16 rowacc = {};
    float diagacc = 0.f;

    for (int ct = 0; ct < NCT; ++ct) {
        f32x16 acc = {};
#pragma unroll
        for (int kh = 0; kh < 2; ++kh) {
            const int s = ct * 2 + kh;
            // prefetch distance 2 (sub-tiles); tail: dummy re-stage of
            // sub-tile NSUB-1 into the dead target buffer keeps the
            // in-flight count uniform at 4.
            const int sn = (s + 2 < NSUB) ? s + 2 : NSUB - 1;
            STAGE(sn, (s + 2) & 3);

            // wait for sub-tile s only (s+1, s+2 = 4 insts stay in flight),
            // then a raw barrier -- NO vmcnt(0) drain.
            __builtin_amdgcn_s_waitcnt(WAITCNT_VM4);
            __builtin_amdgcn_s_barrier();

            const unsigned char* bbuf = ldsB[s & 3] + lane * 16;
#pragma unroll
            for (int ks = 0; ks < 8; ++ks) {
                bf16x8 b = *(const bf16x8*)(bbuf + ks * 1024);
                acc = __builtin_amdgcn_mfma_f32_32x32x16_bf16(
                          a[kh * 8 + ks], b, acc, 0, 0, 0);
            }
        }

        // epilogue once per col-tile: exp-sum
#pragma unroll
        for (int g = 0; g < 16; ++g)
            rowacc[g] += __expf(fmaf(acc[g], INV_T, -INV_T));

        // diagonal tile: wave-uniform, at most 1 of 8 col-tiles
        if (col0 + ct * 32 == row0) {
#pragma unroll
            for (int g = 0; g < 16; ++g) {
                int rm = (g & 3) + 8 * (g >> 2) + 4 * hi;
                if (l31 == rm) diagacc += acc[g] * INV_T;
            }
        }
    }

    // ---- once per block: reduce across the 32 column-lanes, then atomics ----
#pragma unroll
    for (int g = 0; g < 16; ++g) {
        float s = rowacc[g];
        s += __shfl_xor(s, 1, 64);
        s += __shfl_xor(s, 2, 64);
        s += __shfl_xor(s, 4, 64);
        s += __shfl_xor(s, 8, 64);
        s += __shfl_xor(s, 16, 64);
        if (l31 == 0) {
            int grow = row0 + (g & 3) + 8 * (g >> 2) + 4 * hi;
            atomicAdd(&rowsum[grow], s);
        }
    }

    float dsum = diagacc;
#pragma unroll
    for (int off = 32; off; off >>= 1) dsum += __shfl_xor(dsum, off, 64);
    if (lane == 0 && dsum != 0.f) atomicAdd(diagsum, dsum);

    // ---- ticket: last block computes the loss ----
    __syncthreads();
    if (tid == 0) {
        __threadfence();
        int old = __hip_atomic_fetch_add(ticket, 1, __ATOMIC_ACQ_REL,
                                         __HIP_MEMORY_SCOPE_AGENT);
        lastflag = (old == GRID_GEMM - 1);
    }
    __syncthreads();
    if (!lastflag) return;

    float lsum = 0.f;
    for (int rr = tid; rr < B_DIM; rr += 256) {
        float rs = __hip_atomic_load(&rowsum[rr], __ATOMIC_RELAXED,
                                     __HIP_MEMORY_SCOPE_AGENT);
        lsum += __logf(rs);
    }
#pragma unroll
    for (int off = 32; off; off >>= 1) lsum += __shfl_xor(lsum, off, 64);
    if (lane == 0) wred[w] = lsum;
    __syncthreads();
    if (tid == 0) {
        float ds = __hip_atomic_load(diagsum, __ATOMIC_RELAXED,
                                     __HIP_MEMORY_SCOPE_AGENT);
        float total = wred[0] + wred[1] + wred[2] + wred[3]
                    + (float)B_DIM * INV_T   // + M per row
                    - ds;                    // - positive logits
        out[0] = total / (float)B_DIM;
    }
}

extern "C" void kernel_launch(void* const* d_in, const int* in_sizes, int n_in,
                              void* d_out, int out_size, void* d_ws, size_t ws_size,
                              hipStream_t stream)
{
    const float* h = (const float*)d_in[0];
    const float* r = (const float*)d_in[1];
    const float* t = (const float*)d_in[2];

    unsigned char* ws = (unsigned char*)d_ws;
    unsigned short* qws = (unsigned short*)ws;                        // 4 MB (frag order)
    unsigned short* tws = (unsigned short*)(ws + 4u * 1024 * 1024);   // 4 MB (frag order)
    float* rowsum  = (float*)(ws + 8u * 1024 * 1024);                 // 32 KB
    float* diagsum = (float*)(ws + 8u * 1024 * 1024 + 32u * 1024);
    int*   ticket  = (int*)  (ws + 8u * 1024 * 1024 + 32u * 1024 + 16);

    norm_kernel<<<1024, 256, 0, stream>>>(h, r, t, qws, tws, rowsum, diagsum, ticket);
    gemm_lse_kernel<<<GRID_GEMM, 256, 0, stream>>>(
        (const unsigned char*)qws, (const unsigned char*)tws,
        rowsum, diagsum, ticket, (float*)d_out);
}

// Round 12
// 131.965 us; speedup vs baseline: 1.4578x; 1.4578x over previous
//
#include <hip/hip_runtime.h>
#include <hip/hip_bf16.h>

#define B_DIM 8192
#define D_DIM 256
#define GRID_GEMM 512
#define NT 16   // 32-col tiles per block (512 cols per block)

constexpr float INV_T = 14.285714285714286f;   // 1/0.07; also the logsumexp shift M

typedef __bf16 bf16x8 __attribute__((ext_vector_type(8)));
typedef float  f32x16 __attribute__((ext_vector_type(16)));

#define GLOBAL_U32(p) ((const __attribute__((address_space(1))) unsigned int*)(p))
#define LDS_U32(p)    ((__attribute__((address_space(3))) unsigned int*)(p))

// s_waitcnt imm (gfx9): vm[3:0]=bits3:0, exp=bits6:4, lgkm=bits11:8, vm[5:4]=bits15:14
// vmcnt(0), expcnt/lgkmcnt = no-wait:
#define WAITCNT_VM0 0x0F70

__device__ inline unsigned short f2bf(float f) {
    union { float f; unsigned u; } x; x.f = f;
    unsigned r = x.u + 0x7fffu + ((x.u >> 16) & 1u);  // RNE
    return (unsigned short)(r >> 16);
}

// Kernel 1: q = normalize(h+r) * INV_T (pre-scaled so the GEMM's acc is the
// logit z directly), t = normalize(t); BOTH stored in MFMA FRAGMENT order:
// 16B-slot ((row>>5)*16 + ks)*64 + hi*32 + (row&31) holds row's
// k = ks*16 + hi*8 + j (verified R5/R7/R8). bf16 relative precision is
// scale-invariant, so pre-scaling costs no accuracy.
// Block 0 additionally zeroes rowsum/diagsum/ticket.
__global__ __launch_bounds__(256) void norm_kernel(
    const float* __restrict__ h, const float* __restrict__ r,
    const float* __restrict__ t,
    unsigned short* __restrict__ qws, unsigned short* __restrict__ tws,
    float* __restrict__ rowsum, float* __restrict__ diagsum, int* __restrict__ ticket)
{
    if (blockIdx.x == 0) {
        float4* rs4 = (float4*)rowsum;
#pragma unroll
        for (int i = 0; i < 8; ++i)
            rs4[threadIdx.x * 8 + i] = make_float4(0.f, 0.f, 0.f, 0.f);
        if (threadIdx.x == 0) { *diagsum = 0.f; *ticket = 0; }
    }

    const int wave = threadIdx.x >> 6;
    const int lane = threadIdx.x & 63;
    const int wg   = blockIdx.x * 4 + wave;      // 0..4095, 2 rows each

    // fragment store coords for this lane (k = 4*lane + j):
    const int ks  = lane >> 2;
    const int hi2 = (lane >> 1) & 1;
    const int sub = lane & 1;

#pragma unroll
    for (int i = 0; i < 2; ++i) {
        const int row = wg * 2 + i;              // 0..8191
        // ---- q = normalize(h+r) * INV_T ----
        {
            float4 a = ((const float4*)h)[row * 64 + lane];
            float4 b = ((const float4*)r)[row * 64 + lane];
            float4 v = make_float4(a.x + b.x, a.y + b.y, a.z + b.z, a.w + b.w);
            float s = v.x * v.x + v.y * v.y + v.z * v.z + v.w * v.w;
#pragma unroll
            for (int off = 32; off; off >>= 1) s += __shfl_xor(s, off, 64);
            float scale = INV_T / fmaxf(sqrtf(s), 1e-12f);
            ushort4 o;
            o.x = f2bf(v.x * scale); o.y = f2bf(v.y * scale);
            o.z = f2bf(v.z * scale); o.w = f2bf(v.w * scale);
            size_t slot16 = ((size_t)((row >> 5) * 16 + ks) * 64
                             + (size_t)(hi2 * 32 + (row & 31)));
            *(ushort4*)((unsigned char*)qws + slot16 * 16 + sub * 8) = o;
        }
        // ---- t = normalize(t) ----
        {
            float4 v = ((const float4*)t)[row * 64 + lane];
            float s = v.x * v.x + v.y * v.y + v.z * v.z + v.w * v.w;
#pragma unroll
            for (int off = 32; off; off >>= 1) s += __shfl_xor(s, off, 64);
            float scale = 1.0f / fmaxf(sqrtf(s), 1e-12f);
            ushort4 o;
            o.x = f2bf(v.x * scale); o.y = f2bf(v.y * scale);
            o.z = f2bf(v.z * scale); o.w = f2bf(v.w * scale);
            size_t slot16 = ((size_t)((row >> 5) * 16 + ks) * 64
                             + (size_t)(hi2 * 32 + (row & 31)));
            *(ushort4*)((unsigned char*)tws + slot16 * 16 + sub * 8) = o;
        }
    }
}

// Kernel 2: R8's verified structure (64 rows/wave, a[2][16], acc0/acc1 dual
// chains, fragment-order linear staging/reads) with HALVED sync density:
// 8 rounds x 2 tiles, one vmcnt(0)+barrier per round (T3-minimal pattern).
// Per round: vmcnt(0) [drains the pair staged one full compute-phase ago --
// pre-satisfied] -> barrier [legalizes overwriting the pair read last round]
// -> STAGE next pair into the opposite buffers -> process tile 2r then 2r+1
// sequentially reusing acc0/acc1 (register-neutral; 64 MFMA per barrier,
// was 32). R8->R9->R10 showed time tracks syncs-per-MFMA; this pushes that
// lever in the winning direction. Epilogue: acc IS z (q pre-scaled), so
// exp(z-M) = __expf(acc - INV_T), no fma; diag adds acc directly.
__global__ __launch_bounds__(256, 2) void gemm_lse_kernel(
    const unsigned char* __restrict__ qws, const unsigned char* __restrict__ tws,
    float* __restrict__ rowsum, float* __restrict__ diagsum,
    int* __restrict__ ticket, float* __restrict__ out)
{
    __shared__ __align__(16) unsigned char ldsB[4][32 * 512];   // 64 KB
    __shared__ float wred[4];
    __shared__ int lastflag;

    const int tid  = threadIdx.x;
    const int lane = tid & 63;
    const int w    = tid >> 6;
    const int l31  = lane & 31;
    const int hi   = lane >> 5;

    const int cc   = blockIdx.x & 15;        // col chunk (fast -> XCD locality)
    const int rb   = blockIdx.x >> 4;        // row block 0..31
    const int row0 = rb * 256 + w * 64;      // this wave's 64 rows
    const int col0 = cc * 512;
    const int tile0 = cc * 16;               // first 32-col tile of this chunk

    // stage tile st (16 KB, fragment-order = linear) into buffer bufi
#define STAGE(st, bufi)                                                      \
    {                                                                        \
        const unsigned char* gs = tws + (size_t)(tile0 + (st)) * 16384;      \
        _Pragma("unroll")                                                    \
        for (int it = 0; it < 4; ++it)                                       \
            __builtin_amdgcn_global_load_lds(                                \
                GLOBAL_U32(gs + (it * 256 + tid) * 16),                      \
                LDS_U32(&ldsB[bufi][(it * 256 + tid) * 16]), 16, 0, 0);      \
    }

    // prologue: tiles 0 and 1 in flight before the A-fragment loads
    STAGE(0, 0);
    STAGE(1, 1);

    // ---- A fragments in registers: rows row0..row0+63, full K=256 ----
    // frag-order qws: byte = row0*512 + rt*16384 + ks*1024 + lane*16
    // -> row = row0 + rt*32 + l31, k = ks*16 + hi*8 + j
    bf16x8 a[2][16];
    {
        const unsigned char* abase = qws + (size_t)row0 * 512 + lane * 16;
#pragma unroll
        for (int rt = 0; rt < 2; ++rt)
#pragma unroll
            for (int ks = 0; ks < 16; ++ks)
                a[rt][ks] = *(const bf16x8*)(abase + rt * 16384 + ks * 1024);
    }

    f32x16 rowacc[2] = {};
    float diagacc = 0.f;

    // process one 32-col tile t out of the already-resident buffer
#define PROCESS_TILE(t)                                                      \
    {                                                                        \
        const unsigned char* bbuf = ldsB[(t) & 3] + lane * 16;               \
        f32x16 acc0 = {}, acc1 = {};                                         \
        _Pragma("unroll")                                                    \
        for (int ks = 0; ks < 16; ++ks) {                                    \
            bf16x8 b = *(const bf16x8*)(bbuf + ks * 1024);                   \
            acc0 = __builtin_amdgcn_mfma_f32_32x32x16_bf16(a[0][ks], b, acc0, 0, 0, 0); \
            acc1 = __builtin_amdgcn_mfma_f32_32x32x16_bf16(a[1][ks], b, acc1, 0, 0, 0); \
        }                                                                    \
        _Pragma("unroll")                                                    \
        for (int g = 0; g < 16; ++g) {                                       \
            rowacc[0][g] += __expf(acc0[g] - INV_T);                         \
            rowacc[1][g] += __expf(acc1[g] - INV_T);                         \
        }                                                                    \
        const int c0t = col0 + (t) * 32;                                     \
        if (c0t == row0) {                                                   \
            _Pragma("unroll")                                                \
            for (int g = 0; g < 16; ++g) {                                   \
                int rm = (g & 3) + 8 * (g >> 2) + 4 * hi;                    \
                if (l31 == rm) diagacc += acc0[g];                           \
            }                                                                \
        }                                                                    \
        if (c0t == row0 + 32) {                                              \
            _Pragma("unroll")                                                \
            for (int g = 0; g < 16; ++g) {                                   \
                int rm = (g & 3) + 8 * (g >> 2) + 4 * hi;                    \
                if (l31 == rm) diagacc += acc1[g];                           \
            }                                                                \
        }                                                                    \
    }

    for (int r = 0; r < 8; ++r) {
        // drain: the pair read this round was staged one full compute phase
        // ago (or in the prologue), so this wait is normally pre-satisfied.
        __builtin_amdgcn_s_waitcnt(WAITCNT_VM0);
        __builtin_amdgcn_s_barrier();
        // stage the NEXT pair into the opposite buffers; the barrier above
        // guarantees every wave finished reading them last round.
        if (r < 7) {
            STAGE(2 * r + 2, (2 * r + 2) & 3);
            STAGE(2 * r + 3, (2 * r + 3) & 3);
        }
        PROCESS_TILE(2 * r);
        PROCESS_TILE(2 * r + 1);
    }

    // ---- once per block: reduce across the 32 column-lanes, then atomics ----
#pragma unroll
    for (int rt = 0; rt < 2; ++rt)
#pragma unroll
        for (int g = 0; g < 16; ++g) {
            float s = rowacc[rt][g];
            s += __shfl_xor(s, 1, 64);
            s += __shfl_xor(s, 2, 64);
            s += __shfl_xor(s, 4, 64);
            s += __shfl_xor(s, 8, 64);
            s += __shfl_xor(s, 16, 64);
            if (l31 == 0) {
                int grow = row0 + rt * 32 + (g & 3) + 8 * (g >> 2) + 4 * hi;
                atomicAdd(&rowsum[grow], s);
            }
        }

    float dsum = diagacc;
#pragma unroll
    for (int off = 32; off; off >>= 1) dsum += __shfl_xor(dsum, off, 64);
    if (lane == 0 && dsum != 0.f) atomicAdd(diagsum, dsum);

    // ---- ticket: last block computes the loss ----
    __syncthreads();
    if (tid == 0) {
        __threadfence();
        int old = __hip_atomic_fetch_add(ticket, 1, __ATOMIC_ACQ_REL,
                                         __HIP_MEMORY_SCOPE_AGENT);
        lastflag = (old == GRID_GEMM - 1);
    }
    __syncthreads();
    if (!lastflag) return;

    float lsum = 0.f;
    for (int rr = tid; rr < B_DIM; rr += 256) {
        float rs = __hip_atomic_load(&rowsum[rr], __ATOMIC_RELAXED,
                                     __HIP_MEMORY_SCOPE_AGENT);
        lsum += __logf(rs);
    }
#pragma unroll
    for (int off = 32; off; off >>= 1) lsum += __shfl_xor(lsum, off, 64);
    if (lane == 0) wred[w] = lsum;
    __syncthreads();
    if (tid == 0) {
        float ds = __hip_atomic_load(diagsum, __ATOMIC_RELAXED,
                                     __HIP_MEMORY_SCOPE_AGENT);
        float total = wred[0] + wred[1] + wred[2] + wred[3]
                    + (float)B_DIM * INV_T   // + M per row
                    - ds;                    // - positive logits (acc is z)
        out[0] = total / (float)B_DIM;
    }
}

extern "C" void kernel_launch(void* const* d_in, const int* in_sizes, int n_in,
                              void* d_out, int out_size, void* d_ws, size_t ws_size,
                              hipStream_t stream)
{
    const float* h = (const float*)d_in[0];
    const float* r = (const float*)d_in[1];
    const float* t = (const float*)d_in[2];

    unsigned char* ws = (unsigned char*)d_ws;
    unsigned short* qws = (unsigned short*)ws;                        // 4 MB (frag order, pre-scaled)
    unsigned short* tws = (unsigned short*)(ws + 4u * 1024 * 1024);   // 4 MB (frag order)
    float* rowsum  = (float*)(ws + 8u * 1024 * 1024);                 // 32 KB
    float* diagsum = (float*)(ws + 8u * 1024 * 1024 + 32u * 1024);
    int*   ticket  = (int*)  (ws + 8u * 1024 * 1024 + 32u * 1024 + 16);

    norm_kernel<<<1024, 256, 0, stream>>>(h, r, t, qws, tws, rowsum, diagsum, ticket);
    gemm_lse_kernel<<<GRID_GEMM, 256, 0, stream>>>(
        (const unsigned char*)qws, (const unsigned char*)tws,
        rowsum, diagsum, ticket, (float*)d_out);
}

// Round 13
// 125.493 us; speedup vs baseline: 1.5330x; 1.0516x over previous
//
#include <hip/hip_runtime.h>
#include <hip/hip_bf16.h>

#define B_DIM 8192
#define D_DIM 256
#define GRID_GEMM 512
#define NT 16   // 32-col tiles per block (512 cols per block)

constexpr float INV_T = 14.285714285714286f;   // 1/0.07; also the logsumexp shift M

typedef __bf16 bf16x8 __attribute__((ext_vector_type(8)));
typedef float  f32x4  __attribute__((ext_vector_type(4)));

#define GLOBAL_U32(p) ((const __attribute__((address_space(1))) unsigned int*)(p))
#define LDS_U32(p)    ((__attribute__((address_space(3))) unsigned int*)(p))

// s_waitcnt imm (gfx9): vm[3:0]=bits3:0, exp=bits6:4, lgkm=bits11:8, vm[5:4]=bits15:14
// vmcnt(0), expcnt/lgkmcnt = no-wait:
#define WAITCNT_VM0 0x0F70

__device__ inline unsigned short f2bf(float f) {
    union { float f; unsigned u; } x; x.f = f;
    unsigned r = x.u + 0x7fffu + ((x.u >> 16) & 1u);  // RNE
    return (unsigned short)(r >> 16);
}

// Kernel 1: q = normalize(h+r) * INV_T, t = normalize(t); BOTH stored in
// 16x16x32-MFMA FRAGMENT order: 16B-slot ((row>>4)*8 + (k>>5))*64 +
// ((k>>3)&3)*16 + (row&15) holds k-run [k&~7 .. +8). GEMM lane l reads
// slot (l>>4)*16 + (l&15): row=(l&15), k-run=(l>>4) -- coalesced 1KB/inst.
// (k-run ordering only needs A/B to AGREE -- same transform for both.)
// Block 0 additionally zeroes rowsum/diagsum/ticket.
__global__ __launch_bounds__(256) void norm_kernel(
    const float* __restrict__ h, const float* __restrict__ r,
    const float* __restrict__ t,
    unsigned short* __restrict__ qws, unsigned short* __restrict__ tws,
    float* __restrict__ rowsum, float* __restrict__ diagsum, int* __restrict__ ticket)
{
    if (blockIdx.x == 0) {
        float4* rs4 = (float4*)rowsum;
#pragma unroll
        for (int i = 0; i < 8; ++i)
            rs4[threadIdx.x * 8 + i] = make_float4(0.f, 0.f, 0.f, 0.f);
        if (threadIdx.x == 0) { *diagsum = 0.f; *ticket = 0; }
    }

    const int wave = threadIdx.x >> 6;
    const int lane = threadIdx.x & 63;
    const int wg   = blockIdx.x * 4 + wave;      // 0..4095, 2 rows each

    // fragment store coords for this lane (k = 4*lane + j'):
    const int kst  = lane >> 3;          // k>>5
    const int krun = (lane >> 1) & 3;    // (k>>3)&3
    const int sub8 = lane & 1;           // (k>>2)&1 within the 8-run

#pragma unroll
    for (int i = 0; i < 2; ++i) {
        const int row = wg * 2 + i;              // 0..8191
        // ---- q = normalize(h+r) * INV_T ----
        {
            float4 a = ((const float4*)h)[row * 64 + lane];
            float4 b = ((const float4*)r)[row * 64 + lane];
            float4 v = make_float4(a.x + b.x, a.y + b.y, a.z + b.z, a.w + b.w);
            float s = v.x * v.x + v.y * v.y + v.z * v.z + v.w * v.w;
#pragma unroll
            for (int off = 32; off; off >>= 1) s += __shfl_xor(s, off, 64);
            float scale = INV_T / fmaxf(sqrtf(s), 1e-12f);
            ushort4 o;
            o.x = f2bf(v.x * scale); o.y = f2bf(v.y * scale);
            o.z = f2bf(v.z * scale); o.w = f2bf(v.w * scale);
            size_t slot16 = ((size_t)((row >> 4) * 8 + kst) * 64
                             + (size_t)(krun * 16 + (row & 15)));
            *(ushort4*)((unsigned char*)qws + slot16 * 16 + sub8 * 8) = o;
        }
        // ---- t = normalize(t) ----
        {
            float4 v = ((const float4*)t)[row * 64 + lane];
            float s = v.x * v.x + v.y * v.y + v.z * v.z + v.w * v.w;
#pragma unroll
            for (int off = 32; off; off >>= 1) s += __shfl_xor(s, off, 64);
            float scale = 1.0f / fmaxf(sqrtf(s), 1e-12f);
            ushort4 o;
            o.x = f2bf(v.x * scale); o.y = f2bf(v.y * scale);
            o.z = f2bf(v.z * scale); o.w = f2bf(v.w * scale);
            size_t slot16 = ((size_t)((row >> 4) * 8 + kst) * 64
                             + (size_t)(krun * 16 + (row & 15)));
            *(ushort4*)((unsigned char*)tws + slot16 * 16 + sub8 * 8) = o;
        }
    }
}

// Kernel 2: R12's verified sync skeleton (4x16KB ring, 8 rounds x 2 tiles,
// one vmcnt(0)+barrier per round, STAGE pair after barrier) with the MFMA
// shape switched 32x32x16 -> 16x16x32. Why: per-SIMD dependent streams were
// 2 waves x 2 chains = 4 x 8-cyc issue = 32 cyc < MFMA latency -> ~50%
// hard ceiling (R12 measured 21% util; occupancy levers triple-falsified
// R7/R9/R10). Now acc[4][2] f32x4 = 8 chains/wave (16 streams/SIMD, revisit
// 40 cyc) at the SAME 32 acc regs; B-frags shared across 4 row-chains ->
// ds_reads halve (16/tile); issue cost +25% (2075 vs 2382 TF) -- good trade
// when latency-bound. A = a[4][8] (128 regs, AGPR-placed as before).
// C/D: col=lane&15, row=(lane>>4)*4+reg (m89-verified). q pre-scaled: acc
// IS the logit z; exp(z-M) = __expf(acc - INV_T); diag adds acc directly.
__global__ __launch_bounds__(256, 2) void gemm_lse_kernel(
    const unsigned char* __restrict__ qws, const unsigned char* __restrict__ tws,
    float* __restrict__ rowsum, float* __restrict__ diagsum,
    int* __restrict__ ticket, float* __restrict__ out)
{
    __shared__ __align__(16) unsigned char ldsB[4][32 * 512];   // 64 KB
    __shared__ float wred[4];
    __shared__ int lastflag;

    const int tid  = threadIdx.x;
    const int lane = tid & 63;
    const int w    = tid >> 6;
    const int l15  = lane & 15;
    const int hi4  = lane >> 4;

    const int cc   = blockIdx.x & 15;        // col chunk (fast -> XCD locality)
    const int rb   = blockIdx.x >> 4;        // row block 0..31
    const int row0 = rb * 256 + w * 64;      // this wave's 64 rows
    const int col0 = cc * 512;
    const int tile0 = cc * 16;               // first 32-col tile of this chunk

    // stage tile st (16 KB = col-group pair, fragment-order = linear) into bufi
#define STAGE(st, bufi)                                                      \
    {                                                                        \
        const unsigned char* gs = tws + (size_t)(tile0 + (st)) * 16384;      \
        _Pragma("unroll")                                                    \
        for (int it = 0; it < 4; ++it)                                       \
            __builtin_amdgcn_global_load_lds(                                \
                GLOBAL_U32(gs + (it * 256 + tid) * 16),                      \
                LDS_U32(&ldsB[bufi][(it * 256 + tid) * 16]), 16, 0, 0);      \
    }

    // prologue: tiles 0 and 1 in flight before the A-fragment loads
    STAGE(0, 0);
    STAGE(1, 1);

    // ---- A fragments in registers: rows row0..row0+63, full K=256 ----
    // frag-order qws: byte = row0*512 + r*8192 + kst*1024 + lane*16
    // -> row = row0 + r*16 + (lane&15), k-run = (lane>>4), kst = k>>5
    bf16x8 a[4][8];
    {
        const unsigned char* abase = qws + (size_t)row0 * 512 + lane * 16;
#pragma unroll
        for (int r = 0; r < 4; ++r)
#pragma unroll
            for (int kst = 0; kst < 8; ++kst)
                a[r][kst] = *(const bf16x8*)(abase + r * 8192 + kst * 1024);
    }

    float rowacc[16] = {};
    float diagacc = 0.f;

    // process one 32-col tile t (2 col-frags x 8 k-steps, 64 MFMA, 8 chains)
#define PROCESS_TILE(t)                                                      \
    {                                                                        \
        const unsigned char* bbuf = ldsB[(t) & 3] + lane * 16;               \
        f32x4 acc[4][2] = {};                                                \
        _Pragma("unroll")                                                    \
        for (int kst = 0; kst < 8; ++kst) {                                  \
            bf16x8 b0 = *(const bf16x8*)(bbuf + kst * 1024);                 \
            bf16x8 b1 = *(const bf16x8*)(bbuf + 8192 + kst * 1024);          \
            _Pragma("unroll")                                                \
            for (int r = 0; r < 4; ++r) {                                    \
                acc[r][0] = __builtin_amdgcn_mfma_f32_16x16x32_bf16(         \
                                a[r][kst], b0, acc[r][0], 0, 0, 0);          \
                acc[r][1] = __builtin_amdgcn_mfma_f32_16x16x32_bf16(         \
                                a[r][kst], b1, acc[r][1], 0, 0, 0);          \
            }                                                                \
        }                                                                    \
        _Pragma("unroll")                                                    \
        for (int r = 0; r < 4; ++r)                                          \
            _Pragma("unroll")                                                \
            for (int g = 0; g < 4; ++g)                                      \
                rowacc[r * 4 + g] += __expf(acc[r][0][g] - INV_T)            \
                                   + __expf(acc[r][1][g] - INV_T);           \
        const int c0t = col0 + (t) * 32;                                     \
        if (c0t == row0) {                                                   \
            _Pragma("unroll")                                                \
            for (int g = 0; g < 4; ++g)                                      \
                if (l15 == hi4 * 4 + g)                                      \
                    diagacc += acc[0][0][g] + acc[1][1][g];                  \
        }                                                                    \
        if (c0t == row0 + 32) {                                              \
            _Pragma("unroll")                                                \
            for (int g = 0; g < 4; ++g)                                      \
                if (l15 == hi4 * 4 + g)                                      \
                    diagacc += acc[2][0][g] + acc[3][1][g];                  \
        }                                                                    \
    }

    for (int r = 0; r < 8; ++r) {
        // drain: the pair read this round was staged one full compute phase
        // ago (or in the prologue), so this wait is normally pre-satisfied.
        __builtin_amdgcn_s_waitcnt(WAITCNT_VM0);
        __builtin_amdgcn_s_barrier();
        // stage the NEXT pair into the opposite buffers; the barrier above
        // guarantees every wave finished reading them last round.
        if (r < 7) {
            STAGE(2 * r + 2, (2 * r + 2) & 3);
            STAGE(2 * r + 3, (2 * r + 3) & 3);
        }
        PROCESS_TILE(2 * r);
        PROCESS_TILE(2 * r + 1);
    }

    // ---- reduce across the 16 column-lanes of each group, then atomics ----
    // rowacc[rr]: row = row0 + (rr>>2)*16 + hi4*4 + (rr&3); 16 lanes share a
    // row (same hi4, all l15) -> xor-reduce over low 4 lane bits.
#pragma unroll
    for (int rr = 0; rr < 16; ++rr) {
        float s = rowacc[rr];
        s += __shfl_xor(s, 1, 64);
        s += __shfl_xor(s, 2, 64);
        s += __shfl_xor(s, 4, 64);
        s += __shfl_xor(s, 8, 64);
        if (l15 == 0) {
            int grow = row0 + (rr >> 2) * 16 + hi4 * 4 + (rr & 3);
            atomicAdd(&rowsum[grow], s);
        }
    }

    float dsum = diagacc;
#pragma unroll
    for (int off = 32; off; off >>= 1) dsum += __shfl_xor(dsum, off, 64);
    if (lane == 0 && dsum != 0.f) atomicAdd(diagsum, dsum);

    // ---- ticket: last block computes the loss ----
    __syncthreads();
    if (tid == 0) {
        __threadfence();
        int old = __hip_atomic_fetch_add(ticket, 1, __ATOMIC_ACQ_REL,
                                         __HIP_MEMORY_SCOPE_AGENT);
        lastflag = (old == GRID_GEMM - 1);
    }
    __syncthreads();
    if (!lastflag) return;

    float lsum = 0.f;
    for (int rr = tid; rr < B_DIM; rr += 256) {
        float rs = __hip_atomic_load(&rowsum[rr], __ATOMIC_RELAXED,
                                     __HIP_MEMORY_SCOPE_AGENT);
        lsum += __logf(rs);
    }
#pragma unroll
    for (int off = 32; off; off >>= 1) lsum += __shfl_xor(lsum, off, 64);
    if (lane == 0) wred[w] = lsum;
    __syncthreads();
    if (tid == 0) {
        float ds = __hip_atomic_load(diagsum, __ATOMIC_RELAXED,
                                     __HIP_MEMORY_SCOPE_AGENT);
        float total = wred[0] + wred[1] + wred[2] + wred[3]
                    + (float)B_DIM * INV_T   // + M per row
                    - ds;                    // - positive logits (acc is z)
        out[0] = total / (float)B_DIM;
    }
}

extern "C" void kernel_launch(void* const* d_in, const int* in_sizes, int n_in,
                              void* d_out, int out_size, void* d_ws, size_t ws_size,
                              hipStream_t stream)
{
    const float* h = (const float*)d_in[0];
    const float* r = (const float*)d_in[1];
    const float* t = (const float*)d_in[2];

    unsigned char* ws = (unsigned char*)d_ws;
    unsigned short* qws = (unsigned short*)ws;                        // 4 MB (frag order, pre-scaled)
    unsigned short* tws = (unsigned short*)(ws + 4u * 1024 * 1024);   // 4 MB (frag order)
    float* rowsum  = (float*)(ws + 8u * 1024 * 1024);                 // 32 KB
    float* diagsum = (float*)(ws + 8u * 1024 * 1024 + 32u * 1024);
    int*   ticket  = (int*)  (ws + 8u * 1024 * 1024 + 32u * 1024 + 16);

    norm_kernel<<<1024, 256, 0, stream>>>(h, r, t, qws, tws, rowsum, diagsum, ticket);
    gemm_lse_kernel<<<GRID_GEMM, 256, 0, stream>>>(
        (const unsigned char*)qws, (const unsigned char*)tws,
        rowsum, diagsum, ticket, (float*)d_out);
}